// Round 11
// baseline (230.575 us; speedup 1.0000x reference)
//
#include <hip/hip_runtime.h>
#include <math.h>

#define S_TOK 2048
#define NEXP  8
#define DDIM  768
#define HDIM  3072
#define KSEL  4096   // S * CAPACITY

typedef __attribute__((ext_vector_type(8))) short short8;
typedef __attribute__((ext_vector_type(4))) float f32x4;
typedef __attribute__((ext_vector_type(2))) unsigned int u32x2;

#define GLOAD_LDS(GP, LP)                                            \
  __builtin_amdgcn_global_load_lds(                                  \
      (__attribute__((address_space(1))) void*)(GP),                 \
      (__attribute__((address_space(3))) void*)(LP), 16, 0, 0)

__device__ __forceinline__ unsigned short f2bf(float f) {
  unsigned u = __float_as_uint(f);
  u += 0x7fffu + ((u >> 16) & 1u);   // round-to-nearest-even
  return (unsigned short)(u >> 16);
}

__device__ __forceinline__ float gelu_fast(float v) {
  float u = 0.7978845608028654f * (v + 0.044715f * v * v * v);
  float t = __expf(-2.0f * fabsf(u));
  float th = (1.0f - t) / (1.0f + t);
  th = copysignf(th, u);
  return 0.5f * v * (1.0f + th);
}

__global__ __launch_bounds__(256) void zero_kernel(float* __restrict__ p, int n) {
  int i = blockIdx.x * 256 + threadIdx.x;
  if (i < n) p[i] = 0.f;
}

__global__ __launch_bounds__(256) void convx_kernel(const float* __restrict__ x,
                                                    short* __restrict__ xb) {
  int i = (blockIdx.x * 256 + threadIdx.x) * 8;
  float4 a = *(const float4*)(x + i);
  float4 b = *(const float4*)(x + i + 4);
  short8 v;
  v[0] = (short)f2bf(a.x); v[1] = (short)f2bf(a.y);
  v[2] = (short)f2bf(a.z); v[3] = (short)f2bf(a.w);
  v[4] = (short)f2bf(b.x); v[5] = (short)f2bf(b.y);
  v[6] = (short)f2bf(b.z); v[7] = (short)f2bf(b.w);
  *(short8*)(xb + i) = v;
}

// chunk-convert W[e][row0+r][col0+n] (fp32, row len ncols_src, nrows_src rows/expert)
// -> dst[(e*nrows + r)*ncols_dst + n] (bf16), for r<nrows, n<ncols_dst, e<8
__global__ __launch_bounds__(256) void convw_kernel(
    const float* __restrict__ src, short* __restrict__ dst,
    int ncols_src, int col0, int ncols_dst, int row0, int nrows, int nrows_src)
{
  long long i = ((long long)blockIdx.x * 256 + threadIdx.x) * 8;
  int n = (int)(i % ncols_dst);
  long long rr = i / ncols_dst;              // e*nrows + r
  int r = (int)(rr % nrows);
  int e = (int)(rr / nrows);
  const float* s = src + ((size_t)e * nrows_src + row0 + r) * ncols_src + col0 + n;
  float4 a = *(const float4*)(s);
  float4 b = *(const float4*)(s + 4);
  short8 v;
  v[0] = (short)f2bf(a.x); v[1] = (short)f2bf(a.y);
  v[2] = (short)f2bf(a.z); v[3] = (short)f2bf(a.w);
  v[4] = (short)f2bf(b.x); v[5] = (short)f2bf(b.y);
  v[6] = (short)f2bf(b.z); v[7] = (short)f2bf(b.w);
  *(short8*)(dst + i) = v;
}

// ---------------- K1: gating (logits + softmax), exact fp32 ----------------
__global__ __launch_bounds__(256) void gate_kernel(
    const float* __restrict__ x, const float* __restrict__ gw,
    float* __restrict__ scores)
{
  int tid  = threadIdx.x;
  int lane = tid & 63;
  int wid  = tid >> 6;
  int token = blockIdx.x * 4 + wid;
  const float* xr = x + (size_t)token * DDIM;

  float acc[NEXP];
#pragma unroll
  for (int e = 0; e < NEXP; ++e) acc[e] = 0.f;

  for (int d = lane; d < DDIM; d += 64) {
    float xv = xr[d];
#pragma unroll
    for (int e = 0; e < NEXP; ++e) acc[e] += xv * gw[e * DDIM + d];
  }
#pragma unroll
  for (int e = 0; e < NEXP; ++e) {
    for (int off = 32; off; off >>= 1) acc[e] += __shfl_down(acc[e], off, 64);
  }
  if (lane == 0) {
    float m = acc[0];
#pragma unroll
    for (int e = 1; e < NEXP; ++e) m = fmaxf(m, acc[e]);
    float p[NEXP], s = 0.f;
#pragma unroll
    for (int e = 0; e < NEXP; ++e) { p[e] = expf(acc[e] - m); s += p[e]; }
    float inv = 1.0f / s;
#pragma unroll
    for (int e = 0; e < NEXP; ++e) scores[e * S_TOK + token] = p[e] * inv;
  }
}

// ---------------- K2: exact global top-k selection ----------------
__device__ unsigned block_scan_excl(unsigned v, volatile unsigned* wsum) {
  int tid = threadIdx.x, lane = tid & 63, wid = tid >> 6;
  __syncthreads();
  unsigned x = v;
#pragma unroll
  for (int off = 1; off < 64; off <<= 1) {
    unsigned t = __shfl_up(x, off, 64);
    if (lane >= off) x += t;
  }
  if (lane == 63) wsum[wid] = x;
  __syncthreads();
  if (tid < 64) {
    unsigned w = (lane < 16) ? wsum[lane] : 0u;
#pragma unroll
    for (int off = 1; off < 16; off <<= 1) {
      unsigned t = __shfl_up(w, off, 64);
      if (lane >= off) w += t;
    }
    if (lane < 16) wsum[lane] = w;
  }
  __syncthreads();
  unsigned woff = (wid > 0) ? wsum[wid - 1] : 0u;
  return woff + (x - v);
}

__global__ __launch_bounds__(1024) void select_kernel(
    const float* __restrict__ scores,
    int* __restrict__ tokenlist, float* __restrict__ slotgate,
    int* __restrict__ offsets)
{
  __shared__ unsigned cnt;
  __shared__ unsigned wsum[16];
  int tid = threadIdx.x;
  int base = tid * 16;

  float sv[16]; unsigned key[16];
#pragma unroll
  for (int j = 0; j < 16; ++j) {
    sv[j] = scores[base + j];
    key[j] = __float_as_uint(sv[j]);
  }

  unsigned lo = 0, hi = 0x3F800000u;
  while (lo < hi) {
    unsigned mid = lo + ((hi - lo + 1) >> 1);
    if (tid == 0) cnt = 0;
    __syncthreads();
    unsigned c = 0;
#pragma unroll
    for (int j = 0; j < 16; ++j) c += (key[j] >= mid) ? 1u : 0u;
    for (int off = 32; off; off >>= 1) c += __shfl_down(c, off, 64);
    if ((tid & 63) == 0) atomicAdd(&cnt, c);
    __syncthreads();
    unsigned tot = cnt;
    __syncthreads();
    if (tot >= (unsigned)KSEL) lo = mid; else hi = mid - 1;
  }
  unsigned V = lo;

  if (tid == 0) cnt = 0;
  __syncthreads();
  {
    unsigned c = 0;
#pragma unroll
    for (int j = 0; j < 16; ++j) c += (key[j] > V) ? 1u : 0u;
    for (int off = 32; off; off >>= 1) c += __shfl_down(c, off, 64);
    if ((tid & 63) == 0) atomicAdd(&cnt, c);
  }
  __syncthreads();
  int need = KSEL - (int)cnt;
  __syncthreads();

  unsigned tloc = 0;
#pragma unroll
  for (int j = 0; j < 16; ++j) tloc += (key[j] == V) ? 1u : 0u;
  unsigned texcl = block_scan_excl(tloc, wsum);

  unsigned selmask = 0, sloc = 0, trun = texcl;
#pragma unroll
  for (int j = 0; j < 16; ++j) {
    bool f;
    if (key[j] > V) f = true;
    else if (key[j] == V) { f = ((int)trun < need); ++trun; }
    else f = false;
    if (f) { selmask |= (1u << j); ++sloc; }
  }
  unsigned sexcl = block_scan_excl(sloc, wsum);

  // expert e starts at flat index e*2048 == thread e*128
  if ((tid & 127) == 0) offsets[tid >> 7] = (int)sexcl;
  if (tid == 0) offsets[NEXP] = KSEL;

  unsigned p = sexcl;
#pragma unroll
  for (int j = 0; j < 16; ++j) {
    int i = base + j;
    if (selmask & (1u << j)) {
      tokenlist[p] = i & (S_TOK - 1);
      slotgate[p] = sv[j];
      ++p;
    }
  }
}

// ------- K3/K4: bf16 MFMA grouped GEMM, 128x128 tile, BK=32, DMA staging -------
// A: global_load_lds (per-lane gathered source) -> linear LDS [128][32] bf16.
// B: global_load_lds with pre-swizzled per-lane source -> m156 subtile layout
//    [kq(8)][ng(8)][4][16] -> proven ds_read_b64_tr_b16 frag reads (offset:1024 pair).
// grid = (expert=8, N/128, tile<<split_bits) -> linear_id % 8 == expert (XCD affinity)
// MODE 1: out hbuf bf16 = gelu(A@W1c + b1[cbias+..]); MODE 2: y atomicAdd gate*(A@W2c + b2)
template <int MODE>
__global__ __launch_bounds__(256) void moe_mfma(
    const short* __restrict__ Abase, const short* __restrict__ Wbf,
    const float* __restrict__ bias, void* __restrict__ outp,
    const int* __restrict__ offsets, const int* __restrict__ tokenlist,
    const float* __restrict__ slotgate,
    int N, int SA, int estride, int split_bits, int cbias, int bias_en)
{
  const int e = (int)blockIdx.x;
  const int tile  = (int)blockIdx.z >> split_bits;
  const int split = (int)blockIdx.z & ((1 << split_bits) - 1);
  const int kb = split * 768;               // klen = 768 always

  const int r0 = offsets[e];
  const int rows = offsets[e + 1] - r0;
  const int rowbase = tile << 7;
  if (rowbase >= rows) return;
  int vr = rows - rowbase; if (vr > 128) vr = 128;
  const int colbase = (int)blockIdx.y << 7;

  __shared__ __align__(16) short As[128 * 32];   // 8 KB linear [row][32]
  __shared__ __align__(16) short Bs[64 * 64];    // 8 KB, 64 tiles of 4x16 bf16
  const unsigned bs_lds = (unsigned)(uintptr_t)&Bs[0];

  const int tid = threadIdx.x;
  const int lane = tid & 63;
  const int wid = tid >> 6;
  const int wr = (wid >> 1) << 6;
  const int wc = (wid & 1) << 6;
  const int l15 = lane & 15;
  const int lq = lane >> 4;

  // ---- A DMA source: instr i (i=0,1): lane -> row (wid*2+i)*16 + (l>>2), k8=(l&3)*8
  const int row0 = (wid * 2) * 16 + (lane >> 2);
  const int row1 = row0 + 16;
  const int cr0 = (row0 < vr) ? row0 : (vr - 1);
  const int cr1 = (row1 < vr) ? row1 : (vr - 1);
  const short *aptr0, *aptr1;
  if (MODE == 1) {
    aptr0 = Abase + (size_t)tokenlist[r0 + rowbase + cr0] * SA + ((lane & 3) << 3);
    aptr1 = Abase + (size_t)tokenlist[r0 + rowbase + cr1] * SA + ((lane & 3) << 3);
  } else {
    aptr0 = Abase + (size_t)(r0 + rowbase + cr0) * SA + kb + ((lane & 3) << 3);
    aptr1 = Abase + (size_t)(r0 + rowbase + cr1) * SA + kb + ((lane & 3) << 3);
  }

  // ---- B DMA source (pre-swizzled to land in subtile layout):
  // instr i: lane -> kq = wid*2+i, ng = l>>3, row = (l&7)>>1, col8 = l&1
  // source elem = (kb + k0 + kq*4 + row)*N + colbase + ng*16 + col8*8
  const short* wb = Wbf + (size_t)e * estride + colbase +
                    ((lane >> 3) << 4) + ((lane & 1) << 3) +
                    (size_t)(kb + ((lane & 7) >> 1)) * N;
  const short* bptr0 = wb + (size_t)(wid * 2 + 0) * 4 * N;
  const short* bptr1 = wb + (size_t)(wid * 2 + 1) * 4 * N;

  // LDS dest bases (shorts), wave-uniform: instr i at wave*1024 + i*512
  const int dst0 = wid * 1024;
  const int dst1 = wid * 1024 + 512;

#define STAGE(K0)                                                 \
  {                                                               \
    GLOAD_LDS(aptr0 + (K0), As + dst0);                           \
    GLOAD_LDS(aptr1 + (K0), As + dst1);                           \
    GLOAD_LDS(bptr0 + (size_t)(K0) * N, Bs + dst0);               \
    GLOAD_LDS(bptr1 + (size_t)(K0) * N, Bs + dst1);               \
  }

  f32x4 acc[4][4];
#pragma unroll
  for (int i = 0; i < 4; ++i)
#pragma unroll
    for (int j = 0; j < 4; ++j) acc[i][j] = (f32x4){0.f, 0.f, 0.f, 0.f};

  STAGE(0);

#pragma unroll 1
  for (int k0 = 0; k0 < 768; k0 += 32) {
    __syncthreads();                      // drains DMA (vmcnt0) + barrier
    short8 af[4], bfr[4];
#pragma unroll
    for (int i = 0; i < 4; ++i)
      af[i] = *(const short8*)&As[(wr + i * 16 + l15) * 32 + lq * 8];
#pragma unroll
    for (int j = 0; j < 4; ++j) {
      unsigned off = bs_lds + ((unsigned)((lq << 4) + (wc >> 4) + j) << 7) +
                     ((unsigned)l15 << 3);
      union { short8 s; u32x2 u[2]; } fb;
      asm volatile("ds_read_b64_tr_b16 %0, %2 offset:0\n\t"
                   "ds_read_b64_tr_b16 %1, %2 offset:1024"
                   : "=&v"(fb.u[0]), "=&v"(fb.u[1]) : "v"(off));
      bfr[j] = fb.s;
    }
    asm volatile("s_waitcnt lgkmcnt(0)" ::: "memory");
    __builtin_amdgcn_sched_barrier(0);
    __syncthreads();                      // all waves done reading LDS
    if (k0 + 32 < 768) STAGE(k0 + 32);    // DMA next step under the MFMAs
#pragma unroll
    for (int i = 0; i < 4; ++i)
#pragma unroll
      for (int j = 0; j < 4; ++j)
        acc[i][j] = __builtin_amdgcn_mfma_f32_16x16x32_bf16(af[i], bfr[j], acc[i][j], 0, 0, 0);
  }

  if (MODE == 1) {
    short* hb = (short*)outp;
    const float* bp = bias + (size_t)e * HDIM + cbias + colbase;
#pragma unroll
    for (int i = 0; i < 4; ++i) {
      int rb = wr + i * 16 + lq * 4;
#pragma unroll
      for (int j = 0; j < 4; ++j) {
        int col = wc + j * 16 + l15;
        float bvv = bp[col];
#pragma unroll
        for (int p = 0; p < 4; ++p) {
          int r = rb + p;
          if (r < vr)
            hb[(size_t)(r0 + rowbase + r) * N + colbase + col] =
                (short)f2bf(gelu_fast(acc[i][j][p] + bvv));
        }
      }
    }
  } else {
    float* y = (float*)outp;
    const float* bp = bias + (size_t)e * DDIM + colbase;
    const int addb = (bias_en && split == 0);
#pragma unroll
    for (int i = 0; i < 4; ++i) {
      int rb = wr + i * 16 + lq * 4;
#pragma unroll
      for (int p = 0; p < 4; ++p) {
        int r = rb + p;
        if (r < vr) {
          int gi = r0 + rowbase + r;
          float g = slotgate[gi];
          float* yrow = y + (size_t)tokenlist[gi] * DDIM + colbase;
#pragma unroll
          for (int j = 0; j < 4; ++j) {
            int col = wc + j * 16 + l15;
            float v = acc[i][j][p] + (addb ? bp[col] : 0.f);
            atomicAdd(&yrow[col], g * v);
          }
        }
      }
    }
  }
#undef STAGE
}

extern "C" void kernel_launch(void* const* d_in, const int* in_sizes, int n_in,
                              void* d_out, int out_size, void* d_ws, size_t ws_size,
                              hipStream_t stream) {
  const float* x  = (const float*)d_in[0];
  const float* gw = (const float*)d_in[1];
  const float* w1 = (const float*)d_in[2];
  const float* b1 = (const float*)d_in[3];
  const float* w2 = (const float*)d_in[4];
  const float* b2 = (const float*)d_in[5];
  float* y = (float*)d_out;

  char* ws = (char*)d_ws;
  float* scores    = (float*)(ws);                    // 64 KB
  int*   tokenlist = (int*)(ws + (64 << 10));         // 16 KB
  float* slotgate  = (float*)(ws + (80 << 10));       // 16 KB
  int*   offsets   = (int*)(ws + (96 << 10));         // 9 ints
  short* xbf       = (short*)(ws + (128 << 10));      // 3 MB

  // chunking: single chunk (NC=3072) if ws fits, else 2 chunks of NC=1536
  const size_t head = (size_t)(128 << 10) + (size_t)S_TOK * DDIM * 2;
  int nchunk = 2;
  {
    size_t need1 = head + (size_t)NEXP * DDIM * HDIM * 2 + (size_t)KSEL * HDIM * 2;
    if (ws_size >= need1) nchunk = 1;
  }
  const int NC = HDIM / nchunk;
  short* wbf  = (short*)(ws + head);
  short* hbuf = wbf + (size_t)NEXP * DDIM * NC;       // after W chunk
  const int estride = DDIM * NC;                      // per-expert elems (both W1c, W2c)
  const int sb2 = (NC == 3072) ? 2 : 1;               // GEMM2 K-splits = NC/768

  zero_kernel<<<(out_size + 255) / 256, 256, 0, stream>>>(y, out_size);
  convx_kernel<<<S_TOK * DDIM / 2048, 256, 0, stream>>>(x, xbf);
  gate_kernel<<<S_TOK / 4, 256, 0, stream>>>(x, gw, scores);
  select_kernel<<<1, 1024, 0, stream>>>(scores, tokenlist, slotgate, offsets);

  for (int c = 0; c < nchunk; ++c) {
    // W1 chunk: [768][NC] per expert, cols c*NC..
    convw_kernel<<<(NEXP * DDIM * NC) / 2048, 256, 0, stream>>>(
        w1, wbf, HDIM, c * NC, NC, 0, DDIM, DDIM);
    dim3 g1(NEXP, NC / 128, 16);
    moe_mfma<1><<<g1, 256, 0, stream>>>(xbf, wbf, b1, hbuf, offsets, tokenlist,
                                        slotgate, NC, DDIM, estride, 0, c * NC, 1);
    // W2 chunk: [NC][768] per expert, rows c*NC..
    convw_kernel<<<(NEXP * NC * DDIM) / 2048, 256, 0, stream>>>(
        w2, wbf, DDIM, 0, DDIM, c * NC, NC, HDIM);
    dim3 g2(NEXP, DDIM / 128, 16 << sb2);
    moe_mfma<2><<<g2, 256, 0, stream>>>(hbuf, wbf, b2, y, offsets, tokenlist,
                                        slotgate, DDIM, NC, estride, sb2, 0, c == 0);
  }
}

// Round 12
// 219.741 us; speedup vs baseline: 1.0493x; 1.0493x over previous
//
#include <hip/hip_runtime.h>
#include <math.h>

#define S_TOK 2048
#define NEXP  8
#define DDIM  768
#define HDIM  3072
#define KSEL  4096   // S * CAPACITY

typedef __attribute__((ext_vector_type(8))) short short8;
typedef __attribute__((ext_vector_type(4))) float f32x4;
typedef __attribute__((ext_vector_type(2))) unsigned int u32x2;

#define GLOAD_LDS(GP, LP)                                            \
  __builtin_amdgcn_global_load_lds(                                  \
      (__attribute__((address_space(1))) void*)(GP),                 \
      (__attribute__((address_space(3))) void*)(LP), 16, 0, 0)

__device__ __forceinline__ unsigned short f2bf(float f) {
  unsigned u = __float_as_uint(f);
  u += 0x7fffu + ((u >> 16) & 1u);   // round-to-nearest-even
  return (unsigned short)(u >> 16);
}

__device__ __forceinline__ float gelu_fast(float v) {
  float u = 0.7978845608028654f * (v + 0.044715f * v * v * v);
  float t = __expf(-2.0f * fabsf(u));
  float th = (1.0f - t) / (1.0f + t);
  th = copysignf(th, u);
  return 0.5f * v * (1.0f + th);
}

__global__ __launch_bounds__(256) void zero_kernel(float* __restrict__ p, int n) {
  int i = blockIdx.x * 256 + threadIdx.x;
  if (i < n) p[i] = 0.f;
}

__global__ __launch_bounds__(256) void convx_kernel(const float* __restrict__ x,
                                                    short* __restrict__ xb) {
  int i = (blockIdx.x * 256 + threadIdx.x) * 8;
  float4 a = *(const float4*)(x + i);
  float4 b = *(const float4*)(x + i + 4);
  short8 v;
  v[0] = (short)f2bf(a.x); v[1] = (short)f2bf(a.y);
  v[2] = (short)f2bf(a.z); v[3] = (short)f2bf(a.w);
  v[4] = (short)f2bf(b.x); v[5] = (short)f2bf(b.y);
  v[6] = (short)f2bf(b.z); v[7] = (short)f2bf(b.w);
  *(short8*)(xb + i) = v;
}

// chunk-convert W[e][row0+r][col0+n] (fp32, row len ncols_src, nrows_src rows/expert)
// -> dst[(e*nrows + r)*ncols_dst + n] (bf16)
__global__ __launch_bounds__(256) void convw_kernel(
    const float* __restrict__ src, short* __restrict__ dst,
    int ncols_src, int col0, int ncols_dst, int row0, int nrows, int nrows_src)
{
  long long i = ((long long)blockIdx.x * 256 + threadIdx.x) * 8;
  int n = (int)(i % ncols_dst);
  long long rr = i / ncols_dst;              // e*nrows + r
  int r = (int)(rr % nrows);
  int e = (int)(rr / nrows);
  const float* s = src + ((size_t)e * nrows_src + row0 + r) * ncols_src + col0 + n;
  float4 a = *(const float4*)(s);
  float4 b = *(const float4*)(s + 4);
  short8 v;
  v[0] = (short)f2bf(a.x); v[1] = (short)f2bf(a.y);
  v[2] = (short)f2bf(a.z); v[3] = (short)f2bf(a.w);
  v[4] = (short)f2bf(b.x); v[5] = (short)f2bf(b.y);
  v[6] = (short)f2bf(b.z); v[7] = (short)f2bf(b.w);
  *(short8*)(dst + i) = v;
}

// ---------------- K1: gating (logits + softmax), exact fp32 ----------------
__global__ __launch_bounds__(256) void gate_kernel(
    const float* __restrict__ x, const float* __restrict__ gw,
    float* __restrict__ scores)
{
  int tid  = threadIdx.x;
  int lane = tid & 63;
  int wid  = tid >> 6;
  int token = blockIdx.x * 4 + wid;
  const float* xr = x + (size_t)token * DDIM;

  float acc[NEXP];
#pragma unroll
  for (int e = 0; e < NEXP; ++e) acc[e] = 0.f;

  for (int d = lane; d < DDIM; d += 64) {
    float xv = xr[d];
#pragma unroll
    for (int e = 0; e < NEXP; ++e) acc[e] += xv * gw[e * DDIM + d];
  }
#pragma unroll
  for (int e = 0; e < NEXP; ++e) {
    for (int off = 32; off; off >>= 1) acc[e] += __shfl_down(acc[e], off, 64);
  }
  if (lane == 0) {
    float m = acc[0];
#pragma unroll
    for (int e = 1; e < NEXP; ++e) m = fmaxf(m, acc[e]);
    float p[NEXP], s = 0.f;
#pragma unroll
    for (int e = 0; e < NEXP; ++e) { p[e] = expf(acc[e] - m); s += p[e]; }
    float inv = 1.0f / s;
#pragma unroll
    for (int e = 0; e < NEXP; ++e) scores[e * S_TOK + token] = p[e] * inv;
  }
}

// ---------------- K2: exact global top-k selection ----------------
__device__ unsigned block_scan_excl(unsigned v, volatile unsigned* wsum) {
  int tid = threadIdx.x, lane = tid & 63, wid = tid >> 6;
  __syncthreads();
  unsigned x = v;
#pragma unroll
  for (int off = 1; off < 64; off <<= 1) {
    unsigned t = __shfl_up(x, off, 64);
    if (lane >= off) x += t;
  }
  if (lane == 63) wsum[wid] = x;
  __syncthreads();
  if (tid < 64) {
    unsigned w = (lane < 16) ? wsum[lane] : 0u;
#pragma unroll
    for (int off = 1; off < 16; off <<= 1) {
      unsigned t = __shfl_up(w, off, 64);
      if (lane >= off) w += t;
    }
    if (lane < 16) wsum[lane] = w;
  }
  __syncthreads();
  unsigned woff = (wid > 0) ? wsum[wid - 1] : 0u;
  return woff + (x - v);
}

__global__ __launch_bounds__(1024) void select_kernel(
    const float* __restrict__ scores,
    int* __restrict__ tokenlist, float* __restrict__ slotgate,
    int* __restrict__ offsets)
{
  __shared__ unsigned cnt;
  __shared__ unsigned wsum[16];
  int tid = threadIdx.x;
  int base = tid * 16;

  float sv[16]; unsigned key[16];
#pragma unroll
  for (int j = 0; j < 16; ++j) {
    sv[j] = scores[base + j];
    key[j] = __float_as_uint(sv[j]);
  }

  unsigned lo = 0, hi = 0x3F800000u;
  while (lo < hi) {
    unsigned mid = lo + ((hi - lo + 1) >> 1);
    if (tid == 0) cnt = 0;
    __syncthreads();
    unsigned c = 0;
#pragma unroll
    for (int j = 0; j < 16; ++j) c += (key[j] >= mid) ? 1u : 0u;
    for (int off = 32; off; off >>= 1) c += __shfl_down(c, off, 64);
    if ((tid & 63) == 0) atomicAdd(&cnt, c);
    __syncthreads();
    unsigned tot = cnt;
    __syncthreads();
    if (tot >= (unsigned)KSEL) lo = mid; else hi = mid - 1;
  }
  unsigned V = lo;

  if (tid == 0) cnt = 0;
  __syncthreads();
  {
    unsigned c = 0;
#pragma unroll
    for (int j = 0; j < 16; ++j) c += (key[j] > V) ? 1u : 0u;
    for (int off = 32; off; off >>= 1) c += __shfl_down(c, off, 64);
    if ((tid & 63) == 0) atomicAdd(&cnt, c);
  }
  __syncthreads();
  int need = KSEL - (int)cnt;
  __syncthreads();

  unsigned tloc = 0;
#pragma unroll
  for (int j = 0; j < 16; ++j) tloc += (key[j] == V) ? 1u : 0u;
  unsigned texcl = block_scan_excl(tloc, wsum);

  unsigned selmask = 0, sloc = 0, trun = texcl;
#pragma unroll
  for (int j = 0; j < 16; ++j) {
    bool f;
    if (key[j] > V) f = true;
    else if (key[j] == V) { f = ((int)trun < need); ++trun; }
    else f = false;
    if (f) { selmask |= (1u << j); ++sloc; }
  }
  unsigned sexcl = block_scan_excl(sloc, wsum);

  // expert e starts at flat index e*2048 == thread e*128
  if ((tid & 127) == 0) offsets[tid >> 7] = (int)sexcl;
  if (tid == 0) offsets[NEXP] = KSEL;

  unsigned p = sexcl;
#pragma unroll
  for (int j = 0; j < 16; ++j) {
    int i = base + j;
    if (selmask & (1u << j)) {
      tokenlist[p] = i & (S_TOK - 1);
      slotgate[p] = sv[j];
      ++p;
    }
  }
}

// ------- K3/K4: bf16 MFMA grouped GEMM, 128x128 tile, BK=32, DMA + counted vmcnt -------
// Double-buffered LDS; raw s_barrier; vmcnt(4) per step (vmcnt(0) only last step).
// A: global_load_lds -> linear [128][32] bf16. B: pre-swizzled source -> m156 subtile
// layout -> proven ds_read_b64_tr_b16 frags (offset:1024 pair).
// grid = (expert=8, N/128, tile<<split_bits) -> linear_id % 8 == expert (XCD affinity)
// MODE 1: hbuf = gelu(A@W1c + b1[cbias..]); MODE 2: y atomicAdd gate*(A@W2c + b2)
template <int MODE>
__global__ __launch_bounds__(256) void moe_mfma(
    const short* __restrict__ Abase, const short* __restrict__ Wbf,
    const float* __restrict__ bias, void* __restrict__ outp,
    const int* __restrict__ offsets, const int* __restrict__ tokenlist,
    const float* __restrict__ slotgate,
    int N, int SA, int estride, int split_bits, int cbias, int bias_en)
{
  const int e = (int)blockIdx.x;
  const int tile  = (int)blockIdx.z >> split_bits;
  const int split = (int)blockIdx.z & ((1 << split_bits) - 1);
  const int kb = split * 768;               // klen = 768 always

  const int r0 = offsets[e];
  const int rows = offsets[e + 1] - r0;
  const int rowbase = tile << 7;
  if (rowbase >= rows) return;
  int vr = rows - rowbase; if (vr > 128) vr = 128;
  const int colbase = (int)blockIdx.y << 7;

  __shared__ __align__(16) short As0[128 * 32];   // 8 KB each, linear [row][32]
  __shared__ __align__(16) short As1[128 * 32];
  __shared__ __align__(16) short Bs0[64 * 64];    // 8 KB each, 64 tiles of 4x16
  __shared__ __align__(16) short Bs1[64 * 64];
  const unsigned bs0_lds = (unsigned)(uintptr_t)&Bs0[0];
  const unsigned bs1_lds = (unsigned)(uintptr_t)&Bs1[0];

  const int tid = threadIdx.x;
  const int lane = tid & 63;
  const int wid = tid >> 6;
  const int wr = (wid >> 1) << 6;
  const int wc = (wid & 1) << 6;
  const int l15 = lane & 15;
  const int lq = lane >> 4;

  // ---- A DMA source: instr i (i=0,1): lane -> row (wid*2+i)*16 + (l>>2), k8=(l&3)*8
  const int row0 = (wid * 2) * 16 + (lane >> 2);
  const int row1 = row0 + 16;
  const int cr0 = (row0 < vr) ? row0 : (vr - 1);
  const int cr1 = (row1 < vr) ? row1 : (vr - 1);
  const short *aptr0, *aptr1;
  if (MODE == 1) {
    aptr0 = Abase + (size_t)tokenlist[r0 + rowbase + cr0] * SA + ((lane & 3) << 3);
    aptr1 = Abase + (size_t)tokenlist[r0 + rowbase + cr1] * SA + ((lane & 3) << 3);
  } else {
    aptr0 = Abase + (size_t)(r0 + rowbase + cr0) * SA + kb + ((lane & 3) << 3);
    aptr1 = Abase + (size_t)(r0 + rowbase + cr1) * SA + kb + ((lane & 3) << 3);
  }

  // ---- B DMA source (pre-swizzled to land in subtile layout):
  // instr i: lane -> kq = wid*2+i, ng = l>>3, row = (l&7)>>1, col8 = l&1
  const short* wb = Wbf + (size_t)e * estride + colbase +
                    ((lane >> 3) << 4) + ((lane & 1) << 3) +
                    (size_t)(kb + ((lane & 7) >> 1)) * N;
  const short* bptr0 = wb + (size_t)(wid * 2 + 0) * 4 * N;
  const short* bptr1 = wb + (size_t)(wid * 2 + 1) * 4 * N;

  // LDS dest bases (shorts), wave-uniform
  const int dst0 = wid * 1024;
  const int dst1 = wid * 1024 + 512;

#define STAGE(K0, ASX, BSX)                                       \
  {                                                               \
    GLOAD_LDS(aptr0 + (K0), (ASX) + dst0);                        \
    GLOAD_LDS(aptr1 + (K0), (ASX) + dst1);                        \
    GLOAD_LDS(bptr0 + (size_t)(K0) * N, (BSX) + dst0);            \
    GLOAD_LDS(bptr1 + (size_t)(K0) * N, (BSX) + dst1);            \
  }

  f32x4 acc[4][4];
#pragma unroll
  for (int i = 0; i < 4; ++i)
#pragma unroll
    for (int j = 0; j < 4; ++j) acc[i][j] = (f32x4){0.f, 0.f, 0.f, 0.f};

#define KSTEP_BODY(ASX, BLDS, STG_COND, STG_K, STG_AS, STG_BS, LASTWAIT)   \
  {                                                               \
    if (LASTWAIT) { asm volatile("s_waitcnt vmcnt(0)" ::: "memory"); }     \
    else          { asm volatile("s_waitcnt vmcnt(4)" ::: "memory"); }     \
    __builtin_amdgcn_s_barrier();                                 \
    __builtin_amdgcn_sched_barrier(0);                            \
    short8 af[4], bfr[4];                                         \
    _Pragma("unroll")                                             \
    for (int i = 0; i < 4; ++i)                                   \
      af[i] = *(const short8*)&ASX[(wr + i * 16 + l15) * 32 + lq * 8];     \
    _Pragma("unroll")                                             \
    for (int j = 0; j < 4; ++j) {                                 \
      unsigned off = (BLDS) + ((unsigned)((lq << 4) + (wc >> 4) + j) << 7) + \
                     ((unsigned)l15 << 3);                        \
      union { short8 s; u32x2 u[2]; } fb;                         \
      asm volatile("ds_read_b64_tr_b16 %0, %2 offset:0\n\t"       \
                   "ds_read_b64_tr_b16 %1, %2 offset:1024"        \
                   : "=&v"(fb.u[0]), "=&v"(fb.u[1]) : "v"(off));  \
      bfr[j] = fb.s;                                              \
    }                                                             \
    asm volatile("s_waitcnt lgkmcnt(0)" ::: "memory");            \
    __builtin_amdgcn_sched_barrier(0);                            \
    __builtin_amdgcn_s_barrier();                                 \
    __builtin_amdgcn_sched_barrier(0);                            \
    if (STG_COND) STAGE(STG_K, STG_AS, STG_BS);                   \
    _Pragma("unroll")                                             \
    for (int i = 0; i < 4; ++i)                                   \
      _Pragma("unroll")                                           \
      for (int j = 0; j < 4; ++j)                                 \
        acc[i][j] = __builtin_amdgcn_mfma_f32_16x16x32_bf16(af[i], bfr[j], acc[i][j], 0, 0, 0); \
  }

  // prologue: two stages in flight
  STAGE(0, As0, Bs0);
  STAGE(32, As1, Bs1);

#pragma unroll 1
  for (int k0 = 0; k0 < 768; k0 += 64) {
    // step A: consume buf0 (@k0); refill buf0 with @k0+64
    KSTEP_BODY(As0, bs0_lds, (k0 + 64 < 768), k0 + 64, As0, Bs0, false);
    // step B: consume buf1 (@k0+32); refill buf1 with @k0+96; last step waits 0
    KSTEP_BODY(As1, bs1_lds, (k0 + 96 < 768), k0 + 96, As1, Bs1, (k0 >= 704));
  }

  if (MODE == 1) {
    short* hb = (short*)outp;
    const float* bp = bias + (size_t)e * HDIM + cbias + colbase;
#pragma unroll
    for (int i = 0; i < 4; ++i) {
      int rb = wr + i * 16 + lq * 4;
#pragma unroll
      for (int j = 0; j < 4; ++j) {
        int col = wc + j * 16 + l15;
        float bvv = bp[col];
#pragma unroll
        for (int p = 0; p < 4; ++p) {
          int r = rb + p;
          if (r < vr)
            hb[(size_t)(r0 + rowbase + r) * N + colbase + col] =
                (short)f2bf(gelu_fast(acc[i][j][p] + bvv));
        }
      }
    }
  } else {
    float* y = (float*)outp;
    const float* bp = bias + (size_t)e * DDIM + colbase;
    const int addb = (bias_en && split == 0);
#pragma unroll
    for (int i = 0; i < 4; ++i) {
      int rb = wr + i * 16 + lq * 4;
#pragma unroll
      for (int p = 0; p < 4; ++p) {
        int r = rb + p;
        if (r < vr) {
          int gi = r0 + rowbase + r;
          float g = slotgate[gi];
          float* yrow = y + (size_t)tokenlist[gi] * DDIM + colbase;
#pragma unroll
          for (int j = 0; j < 4; ++j) {
            int col = wc + j * 16 + l15;
            float v = acc[i][j][p] + (addb ? bp[col] : 0.f);
            atomicAdd(&yrow[col], g * v);
          }
        }
      }
    }
  }
#undef STAGE
#undef KSTEP_BODY
}

extern "C" void kernel_launch(void* const* d_in, const int* in_sizes, int n_in,
                              void* d_out, int out_size, void* d_ws, size_t ws_size,
                              hipStream_t stream) {
  const float* x  = (const float*)d_in[0];
  const float* gw = (const float*)d_in[1];
  const float* w1 = (const float*)d_in[2];
  const float* b1 = (const float*)d_in[3];
  const float* w2 = (const float*)d_in[4];
  const float* b2 = (const float*)d_in[5];
  float* y = (float*)d_out;

  char* ws = (char*)d_ws;
  float* scores    = (float*)(ws);                    // 64 KB
  int*   tokenlist = (int*)(ws + (64 << 10));         // 16 KB
  float* slotgate  = (float*)(ws + (80 << 10));       // 16 KB
  int*   offsets   = (int*)(ws + (96 << 10));         // 9 ints
  short* xbf       = (short*)(ws + (128 << 10));      // 3 MB

  // chunking: single chunk (NC=3072) if ws fits, else 2 chunks of NC=1536
  const size_t head = (size_t)(128 << 10) + (size_t)S_TOK * DDIM * 2;
  int nchunk = 2;
  {
    size_t need1 = head + (size_t)NEXP * DDIM * HDIM * 2 + (size_t)KSEL * HDIM * 2;
    if (ws_size >= need1) nchunk = 1;
  }
  const int NC = HDIM / nchunk;
  short* wbf  = (short*)(ws + head);
  short* hbuf = wbf + (size_t)NEXP * DDIM * NC;       // after W chunk
  const int estride = DDIM * NC;                      // per-expert elems (both W1c, W2c)
  const int sb2 = (NC == 3072) ? 2 : 1;               // GEMM2 K-splits = NC/768

  zero_kernel<<<(out_size + 255) / 256, 256, 0, stream>>>(y, out_size);
  convx_kernel<<<S_TOK * DDIM / 2048, 256, 0, stream>>>(x, xbf);
  gate_kernel<<<S_TOK / 4, 256, 0, stream>>>(x, gw, scores);
  select_kernel<<<1, 1024, 0, stream>>>(scores, tokenlist, slotgate, offsets);

  for (int c = 0; c < nchunk; ++c) {
    // W1 chunk: [768][NC] per expert, cols c*NC..
    convw_kernel<<<(NEXP * DDIM * NC) / 2048, 256, 0, stream>>>(
        w1, wbf, HDIM, c * NC, NC, 0, DDIM, DDIM);
    dim3 g1(NEXP, NC / 128, 16);
    moe_mfma<1><<<g1, 256, 0, stream>>>(xbf, wbf, b1, hbuf, offsets, tokenlist,
                                        slotgate, NC, DDIM, estride, 0, c * NC, 1);
    // W2 chunk: [NC][768] per expert, rows c*NC..
    convw_kernel<<<(NEXP * NC * DDIM) / 2048, 256, 0, stream>>>(
        w2, wbf, DDIM, 0, DDIM, c * NC, NC, HDIM);
    dim3 g2(NEXP, DDIM / 128, 16 << sb2);
    moe_mfma<2><<<g2, 256, 0, stream>>>(hbuf, wbf, b2, y, offsets, tokenlist,
                                        slotgate, DDIM, NC, estride, sb2, 0, c == 0);
  }
}

// Round 13
// 211.350 us; speedup vs baseline: 1.0910x; 1.0397x over previous
//
#include <hip/hip_runtime.h>
#include <math.h>

#define S_TOK 2048
#define NEXP  8
#define DDIM  768
#define HDIM  3072
#define KSEL  4096   // S * CAPACITY

typedef __attribute__((ext_vector_type(8))) short short8;
typedef __attribute__((ext_vector_type(4))) float f32x4;
typedef __attribute__((ext_vector_type(2))) unsigned int u32x2;

#define GLOAD_LDS(GP, LP)                                            \
  __builtin_amdgcn_global_load_lds(                                  \
      (__attribute__((address_space(1))) void*)(GP),                 \
      (__attribute__((address_space(3))) void*)(LP), 16, 0, 0)

#define VMWAIT(N) asm volatile("s_waitcnt vmcnt(" #N ")" ::: "memory")

__device__ __forceinline__ unsigned short f2bf(float f) {
  unsigned u = __float_as_uint(f);
  u += 0x7fffu + ((u >> 16) & 1u);   // round-to-nearest-even
  return (unsigned short)(u >> 16);
}

__device__ __forceinline__ float gelu_fast(float v) {
  float u = 0.7978845608028654f * (v + 0.044715f * v * v * v);
  float t = __expf(-2.0f * fabsf(u));
  float th = (1.0f - t) / (1.0f + t);
  th = copysignf(th, u);
  return 0.5f * v * (1.0f + th);
}

__global__ __launch_bounds__(256) void zero_kernel(float* __restrict__ p, int n) {
  int i = blockIdx.x * 256 + threadIdx.x;
  if (i < n) p[i] = 0.f;
}

// chunk-convert W[e][row0+r][col0+n] (fp32) -> dst[(e*nrows + r)*ncols_dst + n] (bf16)
__global__ __launch_bounds__(256) void convw_kernel(
    const float* __restrict__ src, short* __restrict__ dst,
    int ncols_src, int col0, int ncols_dst, int row0, int nrows, int nrows_src)
{
  long long i = ((long long)blockIdx.x * 256 + threadIdx.x) * 8;
  int n = (int)(i % ncols_dst);
  long long rr = i / ncols_dst;              // e*nrows + r
  int r = (int)(rr % nrows);
  int e = (int)(rr / nrows);
  const float* s = src + ((size_t)e * nrows_src + row0 + r) * ncols_src + col0 + n;
  float4 a = *(const float4*)(s);
  float4 b = *(const float4*)(s + 4);
  short8 v;
  v[0] = (short)f2bf(a.x); v[1] = (short)f2bf(a.y);
  v[2] = (short)f2bf(a.z); v[3] = (short)f2bf(a.w);
  v[4] = (short)f2bf(b.x); v[5] = (short)f2bf(b.y);
  v[6] = (short)f2bf(b.z); v[7] = (short)f2bf(b.w);
  *(short8*)(dst + i) = v;
}

// ---------------- K1: gating (logits + softmax) + x->bf16 conversion ----------------
__global__ __launch_bounds__(256) void gate_kernel(
    const float* __restrict__ x, const float* __restrict__ gw,
    float* __restrict__ scores, short* __restrict__ xb)
{
  int tid  = threadIdx.x;
  int lane = tid & 63;
  int wid  = tid >> 6;
  int token = blockIdx.x * 4 + wid;
  const float* xr = x + (size_t)token * DDIM;
  short* xbr = xb + (size_t)token * DDIM;

  float acc[NEXP];
#pragma unroll
  for (int e = 0; e < NEXP; ++e) acc[e] = 0.f;

  for (int d = lane; d < DDIM; d += 64) {
    float xv = xr[d];
    xbr[d] = (short)f2bf(xv);
#pragma unroll
    for (int e = 0; e < NEXP; ++e) acc[e] += xv * gw[e * DDIM + d];
  }
#pragma unroll
  for (int e = 0; e < NEXP; ++e) {
    for (int off = 32; off; off >>= 1) acc[e] += __shfl_down(acc[e], off, 64);
  }
  if (lane == 0) {
    float m = acc[0];
#pragma unroll
    for (int e = 1; e < NEXP; ++e) m = fmaxf(m, acc[e]);
    float p[NEXP], s = 0.f;
#pragma unroll
    for (int e = 0; e < NEXP; ++e) { p[e] = expf(acc[e] - m); s += p[e]; }
    float inv = 1.0f / s;
#pragma unroll
    for (int e = 0; e < NEXP; ++e) scores[e * S_TOK + token] = p[e] * inv;
  }
}

// ---------------- K2: exact global top-k selection ----------------
__device__ unsigned block_scan_excl(unsigned v, volatile unsigned* wsum) {
  int tid = threadIdx.x, lane = tid & 63, wid = tid >> 6;
  __syncthreads();
  unsigned x = v;
#pragma unroll
  for (int off = 1; off < 64; off <<= 1) {
    unsigned t = __shfl_up(x, off, 64);
    if (lane >= off) x += t;
  }
  if (lane == 63) wsum[wid] = x;
  __syncthreads();
  if (tid < 64) {
    unsigned w = (lane < 16) ? wsum[lane] : 0u;
#pragma unroll
    for (int off = 1; off < 16; off <<= 1) {
      unsigned t = __shfl_up(w, off, 64);
      if (lane >= off) w += t;
    }
    if (lane < 16) wsum[lane] = w;
  }
  __syncthreads();
  unsigned woff = (wid > 0) ? wsum[wid - 1] : 0u;
  return woff + (x - v);
}

__global__ __launch_bounds__(1024) void select_kernel(
    const float* __restrict__ scores,
    int* __restrict__ tokenlist, float* __restrict__ slotgate,
    int* __restrict__ offsets)
{
  __shared__ unsigned cnt;
  __shared__ unsigned wsum[16];
  int tid = threadIdx.x;
  int base = tid * 16;

  float sv[16]; unsigned key[16];
#pragma unroll
  for (int j = 0; j < 16; ++j) {
    sv[j] = scores[base + j];
    key[j] = __float_as_uint(sv[j]);
  }

  unsigned lo = 0, hi = 0x3F800000u;
  while (lo < hi) {
    unsigned mid = lo + ((hi - lo + 1) >> 1);
    if (tid == 0) cnt = 0;
    __syncthreads();
    unsigned c = 0;
#pragma unroll
    for (int j = 0; j < 16; ++j) c += (key[j] >= mid) ? 1u : 0u;
    for (int off = 32; off; off >>= 1) c += __shfl_down(c, off, 64);
    if ((tid & 63) == 0) atomicAdd(&cnt, c);
    __syncthreads();
    unsigned tot = cnt;
    __syncthreads();
    if (tot >= (unsigned)KSEL) lo = mid; else hi = mid - 1;
  }
  unsigned V = lo;

  if (tid == 0) cnt = 0;
  __syncthreads();
  {
    unsigned c = 0;
#pragma unroll
    for (int j = 0; j < 16; ++j) c += (key[j] > V) ? 1u : 0u;
    for (int off = 32; off; off >>= 1) c += __shfl_down(c, off, 64);
    if ((tid & 63) == 0) atomicAdd(&cnt, c);
  }
  __syncthreads();
  int need = KSEL - (int)cnt;
  __syncthreads();

  unsigned tloc = 0;
#pragma unroll
  for (int j = 0; j < 16; ++j) tloc += (key[j] == V) ? 1u : 0u;
  unsigned texcl = block_scan_excl(tloc, wsum);

  unsigned selmask = 0, sloc = 0, trun = texcl;
#pragma unroll
  for (int j = 0; j < 16; ++j) {
    bool f;
    if (key[j] > V) f = true;
    else if (key[j] == V) { f = ((int)trun < need); ++trun; }
    else f = false;
    if (f) { selmask |= (1u << j); ++sloc; }
  }
  unsigned sexcl = block_scan_excl(sloc, wsum);

  // expert e starts at flat index e*2048 == thread e*128
  if ((tid & 127) == 0) offsets[tid >> 7] = (int)sexcl;
  if (tid == 0) offsets[NEXP] = KSEL;

  unsigned p = sexcl;
#pragma unroll
  for (int j = 0; j < 16; ++j) {
    int i = base + j;
    if (selmask & (1u << j)) {
      tokenlist[p] = i & (S_TOK - 1);
      slotgate[p] = sv[j];
      ++p;
    }
  }
}

// ------- K3/K4: bf16 MFMA grouped GEMM, 128x128 tile, BK=32, DMA, 3-deep pipeline -------
// Triple-buffered LDS; raw s_barrier; steady-state vmcnt(8) (drain 8/4/0 at tail).
// A: global_load_lds -> linear [128][32] bf16. B: pre-swizzled source -> m156 subtile
// layout -> proven ds_read_b64_tr_b16 frags (offset:1024 pair).
// grid = (expert=8, N/128, tile<<split_bits) -> linear_id % 8 == expert (XCD affinity)
// MODE 1: hbuf = gelu(A@W1c + b1[cbias..]); MODE 2: y atomicAdd gate*(A@W2c + b2)
template <int MODE>
__global__ __launch_bounds__(256) void moe_mfma(
    const short* __restrict__ Abase, const short* __restrict__ Wbf,
    const float* __restrict__ bias, void* __restrict__ outp,
    const int* __restrict__ offsets, const int* __restrict__ tokenlist,
    const float* __restrict__ slotgate,
    int N, int SA, int estride, int split_bits, int cbias, int bias_en)
{
  const int e = (int)blockIdx.x;
  const int tile  = (int)blockIdx.z >> split_bits;
  const int split = (int)blockIdx.z & ((1 << split_bits) - 1);
  const int kb = split * 768;               // klen = 768 always

  const int r0 = offsets[e];
  const int rows = offsets[e + 1] - r0;
  const int rowbase = tile << 7;
  if (rowbase >= rows) return;
  int vr = rows - rowbase; if (vr > 128) vr = 128;
  const int colbase = (int)blockIdx.y << 7;

  __shared__ __align__(16) short As0[128 * 32];   // 8 KB each, linear [row][32]
  __shared__ __align__(16) short As1[128 * 32];
  __shared__ __align__(16) short As2[128 * 32];
  __shared__ __align__(16) short Bs0[64 * 64];    // 8 KB each, 64 tiles of 4x16
  __shared__ __align__(16) short Bs1[64 * 64];
  __shared__ __align__(16) short Bs2[64 * 64];
  const unsigned bs0_lds = (unsigned)(uintptr_t)&Bs0[0];
  const unsigned bs1_lds = (unsigned)(uintptr_t)&Bs1[0];
  const unsigned bs2_lds = (unsigned)(uintptr_t)&Bs2[0];

  const int tid = threadIdx.x;
  const int lane = tid & 63;
  const int wid = tid >> 6;
  const int wr = (wid >> 1) << 6;
  const int wc = (wid & 1) << 6;
  const int l15 = lane & 15;
  const int lq = lane >> 4;

  // ---- A DMA source: instr i (i=0,1): lane -> row (wid*2+i)*16 + (l>>2), k8=(l&3)*8
  const int row0 = (wid * 2) * 16 + (lane >> 2);
  const int row1 = row0 + 16;
  const int cr0 = (row0 < vr) ? row0 : (vr - 1);
  const int cr1 = (row1 < vr) ? row1 : (vr - 1);
  const short *aptr0, *aptr1;
  if (MODE == 1) {
    aptr0 = Abase + (size_t)tokenlist[r0 + rowbase + cr0] * SA + ((lane & 3) << 3);
    aptr1 = Abase + (size_t)tokenlist[r0 + rowbase + cr1] * SA + ((lane & 3) << 3);
  } else {
    aptr0 = Abase + (size_t)(r0 + rowbase + cr0) * SA + kb + ((lane & 3) << 3);
    aptr1 = Abase + (size_t)(r0 + rowbase + cr1) * SA + kb + ((lane & 3) << 3);
  }

  // ---- B DMA source (pre-swizzled to land in subtile layout):
  // instr i: lane -> kq = wid*2+i, ng = l>>3, row = (l&7)>>1, col8 = l&1
  const short* wb = Wbf + (size_t)e * estride + colbase +
                    ((lane >> 3) << 4) + ((lane & 1) << 3) +
                    (size_t)(kb + ((lane & 7) >> 1)) * N;
  const short* bptr0 = wb + (size_t)(wid * 2 + 0) * 4 * N;
  const short* bptr1 = wb + (size_t)(wid * 2 + 1) * 4 * N;

  // LDS dest bases (shorts), wave-uniform
  const int dst0 = wid * 1024;
  const int dst1 = wid * 1024 + 512;

#define STAGE(K0, ASX, BSX)                                       \
  {                                                               \
    GLOAD_LDS(aptr0 + (K0), (ASX) + dst0);                        \
    GLOAD_LDS(aptr1 + (K0), (ASX) + dst1);                        \
    GLOAD_LDS(bptr0 + (size_t)(K0) * N, (BSX) + dst0);            \
    GLOAD_LDS(bptr1 + (size_t)(K0) * N, (BSX) + dst1);            \
  }

  f32x4 acc[4][4];
#pragma unroll
  for (int i = 0; i < 4; ++i)
#pragma unroll
    for (int j = 0; j < 4; ++j) acc[i][j] = (f32x4){0.f, 0.f, 0.f, 0.f};

#define KSTEP_BODY(ASX, BLDS, STG_COND, STG_K, STG_AS, STG_BS, WAITSTMT)   \
  {                                                               \
    WAITSTMT;                                                     \
    __builtin_amdgcn_s_barrier();                                 \
    __builtin_amdgcn_sched_barrier(0);                            \
    short8 af[4], bfr[4];                                         \
    _Pragma("unroll")                                             \
    for (int i = 0; i < 4; ++i)                                   \
      af[i] = *(const short8*)&ASX[(wr + i * 16 + l15) * 32 + lq * 8];     \
    _Pragma("unroll")                                             \
    for (int j = 0; j < 4; ++j) {                                 \
      unsigned off = (BLDS) + ((unsigned)((lq << 4) + (wc >> 4) + j) << 7) + \
                     ((unsigned)l15 << 3);                        \
      union { short8 s; u32x2 u[2]; } fb;                         \
      asm volatile("ds_read_b64_tr_b16 %0, %2 offset:0\n\t"       \
                   "ds_read_b64_tr_b16 %1, %2 offset:1024"        \
                   : "=&v"(fb.u[0]), "=&v"(fb.u[1]) : "v"(off));  \
      bfr[j] = fb.s;                                              \
    }                                                             \
    asm volatile("s_waitcnt lgkmcnt(0)" ::: "memory");            \
    __builtin_amdgcn_sched_barrier(0);                            \
    __builtin_amdgcn_s_barrier();                                 \
    __builtin_amdgcn_sched_barrier(0);                            \
    if (STG_COND) STAGE(STG_K, STG_AS, STG_BS);                   \
    _Pragma("unroll")                                             \
    for (int i = 0; i < 4; ++i)                                   \
      _Pragma("unroll")                                           \
      for (int j = 0; j < 4; ++j)                                 \
        acc[i][j] = __builtin_amdgcn_mfma_f32_16x16x32_bf16(af[i], bfr[j], acc[i][j], 0, 0, 0); \
  }

  // prologue: three stages in flight (steps 0,1,2)
  STAGE(0, As0, Bs0);
  STAGE(32, As1, Bs1);
  STAGE(64, As2, Bs2);

  // steps 0..20: consume buf s%3 @32s, refill it with step s+3 (@32s+96)
#pragma unroll 1
  for (int k0 = 0; k0 < 672; k0 += 96) {
    KSTEP_BODY(As0, bs0_lds, 1, k0 + 96,  As0, Bs0, VMWAIT(8));
    KSTEP_BODY(As1, bs1_lds, 1, k0 + 128, As1, Bs1, VMWAIT(8));
    KSTEP_BODY(As2, bs2_lds, 1, k0 + 160, As2, Bs2, VMWAIT(8));
  }
  // steps 21 (@672), 22 (@704), 23 (@736): no refill; drain 8/4/0
  KSTEP_BODY(As0, bs0_lds, 0, 0, As0, Bs0, VMWAIT(8));
  KSTEP_BODY(As1, bs1_lds, 0, 0, As1, Bs1, VMWAIT(4));
  KSTEP_BODY(As2, bs2_lds, 0, 0, As2, Bs2, VMWAIT(0));

  if (MODE == 1) {
    short* hb = (short*)outp;
    const float* bp = bias + (size_t)e * HDIM + cbias + colbase;
#pragma unroll
    for (int i = 0; i < 4; ++i) {
      int rb = wr + i * 16 + lq * 4;
#pragma unroll
      for (int j = 0; j < 4; ++j) {
        int col = wc + j * 16 + l15;
        float bvv = bp[col];
#pragma unroll
        for (int p = 0; p < 4; ++p) {
          int r = rb + p;
          if (r < vr)
            hb[(size_t)(r0 + rowbase + r) * N + colbase + col] =
                (short)f2bf(gelu_fast(acc[i][j][p] + bvv));
        }
      }
    }
  } else {
    float* y = (float*)outp;
    const float* bp = bias + (size_t)e * DDIM + colbase;
    const int addb = (bias_en && split == 0);
#pragma unroll
    for (int i = 0; i < 4; ++i) {
      int rb = wr + i * 16 + lq * 4;
#pragma unroll
      for (int p = 0; p < 4; ++p) {
        int r = rb + p;
        if (r < vr) {
          int gi = r0 + rowbase + r;
          float g = slotgate[gi];
          float* yrow = y + (size_t)tokenlist[gi] * DDIM + colbase;
#pragma unroll
          for (int j = 0; j < 4; ++j) {
            int col = wc + j * 16 + l15;
            float v = acc[i][j][p] + (addb ? bp[col] : 0.f);
            atomicAdd(&yrow[col], g * v);
          }
        }
      }
    }
  }
#undef STAGE
#undef KSTEP_BODY
}

extern "C" void kernel_launch(void* const* d_in, const int* in_sizes, int n_in,
                              void* d_out, int out_size, void* d_ws, size_t ws_size,
                              hipStream_t stream) {
  const float* x  = (const float*)d_in[0];
  const float* gw = (const float*)d_in[1];
  const float* w1 = (const float*)d_in[2];
  const float* b1 = (const float*)d_in[3];
  const float* w2 = (const float*)d_in[4];
  const float* b2 = (const float*)d_in[5];
  float* y = (float*)d_out;

  char* ws = (char*)d_ws;
  float* scores    = (float*)(ws);                    // 64 KB
  int*   tokenlist = (int*)(ws + (64 << 10));         // 16 KB
  float* slotgate  = (float*)(ws + (80 << 10));       // 16 KB
  int*   offsets   = (int*)(ws + (96 << 10));         // 9 ints
  short* xbf       = (short*)(ws + (128 << 10));      // 3 MB

  // chunking: single chunk (NC=3072) if ws fits, else 2 chunks of NC=1536
  const size_t head = (size_t)(128 << 10) + (size_t)S_TOK * DDIM * 2;
  int nchunk = 2;
  {
    size_t need1 = head + (size_t)NEXP * DDIM * HDIM * 2 + (size_t)KSEL * HDIM * 2;
    if (ws_size >= need1) nchunk = 1;
  }
  const int NC = HDIM / nchunk;
  short* wbf  = (short*)(ws + head);
  short* hbuf = wbf + (size_t)NEXP * DDIM * NC;       // after W chunk
  const int estride = DDIM * NC;                      // per-expert elems (both W1c, W2c)
  const int sb2 = (NC == 3072) ? 2 : 1;               // GEMM2 K-splits = NC/768

  zero_kernel<<<(out_size + 255) / 256, 256, 0, stream>>>(y, out_size);
  gate_kernel<<<S_TOK / 4, 256, 0, stream>>>(x, gw, scores, xbf);
  select_kernel<<<1, 1024, 0, stream>>>(scores, tokenlist, slotgate, offsets);

  for (int c = 0; c < nchunk; ++c) {
    // W1 chunk: [768][NC] per expert, cols c*NC..
    convw_kernel<<<(NEXP * DDIM * NC) / 2048, 256, 0, stream>>>(
        w1, wbf, HDIM, c * NC, NC, 0, DDIM, DDIM);
    dim3 g1(NEXP, NC / 128, 16);
    moe_mfma<1><<<g1, 256, 0, stream>>>(xbf, wbf, b1, hbuf, offsets, tokenlist,
                                        slotgate, NC, DDIM, estride, 0, c * NC, 1);
    // W2 chunk: [NC][768] per expert, rows c*NC..
    convw_kernel<<<(NEXP * NC * DDIM) / 2048, 256, 0, stream>>>(
        w2, wbf, DDIM, 0, DDIM, c * NC, NC, HDIM);
    dim3 g2(NEXP, DDIM / 128, 16 << sb2);
    moe_mfma<2><<<g2, 256, 0, stream>>>(hbuf, wbf, b2, y, offsets, tokenlist,
                                        slotgate, DDIM, NC, estride, sb2, 0, c == 0);
  }
}